// Round 4
// baseline (1019.511 us; speedup 1.0000x reference)
//
#include <hip/hip_runtime.h>
#include <stdint.h>

typedef __attribute__((ext_vector_type(8))) short short8;
typedef __attribute__((ext_vector_type(4))) float f32x4;

#define DEVFN static __device__ __forceinline__

// ---------------- helpers ----------------
DEVFN float bf2f(uint16_t u) { union { uint32_t i; float f; } v; v.i = ((uint32_t)u) << 16; return v.f; }
DEVFN uint16_t f2bf(float f) {
  union { float f; uint32_t i; } v; v.f = f;
  uint32_t u = v.i;
  u += 0x7fffu + ((u >> 16) & 1u);   // RNE
  return (uint16_t)(u >> 16);
}
DEVFN int imin(int a, int b) { return a < b ? a : b; }

DEVFN void gl_lds16(const void* g, void* l) {
  __builtin_amdgcn_global_load_lds(
      (__attribute__((address_space(1))) void*)(void*)g,
      (__attribute__((address_space(3))) void*)l, 16, 0, 0);
}

DEVFN f32x4 mfma16(short8 a, short8 b, f32x4 c) {
  return __builtin_amdgcn_mfma_f32_16x16x32_bf16(a, b, c, 0, 0, 0);
}

// ---------------- workspace layout (bytes) ----------------
static constexpr size_t OFF_XP   = 0;          // bf16 [64][232][232][4]  x: masked, padded(+3), NHWC4
static constexpr size_t OFF_W1T  = 27557888;   // bf16 [7][64][32]        w1t[kh][oc][kw*4+ic]
static constexpr size_t OFF_W2T  = 27586560;   // bf16 [49][768][64]      w2t[kh*7+kw][oc][ic]
static constexpr size_t OFF_Y1   = 32403456;   // bf16 [64][112][112][64] conv1 out (active cells only)
static constexpr size_t OFF_P1   = 135163904;  // bf16 [64][62][62][64]   pool1 out, padded(+3), NHWC
static constexpr size_t OFF_Y2   = 166653952;  // bf16 [64][28][28][768]  conv2 out (active cells only)
static constexpr size_t OFF_LIST = 243724288;  // int [12544] active cell list, SORTED
static constexpr size_t OFF_CNT  = 243774464;  // int cnts[49] + int total
static constexpr size_t WS_NEED  = 243774664;

// ---------------- stage 0a: per-block mask counts ----------------
__global__ __launch_bounds__(256) void k_count(const int* __restrict__ masks, int* __restrict__ cnts) {
  int b = blockIdx.x;
  int gid = b * 256 + threadIdx.x;   // 49*256 = 12544 exactly
  unsigned long long m = __ballot(masks[gid] != 0);
  __shared__ int wsum[4];
  if ((threadIdx.x & 63) == 0) wsum[threadIdx.x >> 6] = __popcll(m);
  __syncthreads();
  if (threadIdx.x == 0) cnts[b] = wsum[0] + wsum[1] + wsum[2] + wsum[3];
}

// ---------------- stage 0b: deterministic sorted compaction ----------------
__global__ __launch_bounds__(256) void k_emit(const int* __restrict__ masks, const int* __restrict__ cnts,
                                              int* __restrict__ list, int* __restrict__ total) {
  int b = blockIdx.x;
  int gid = b * 256 + threadIdx.x;
  int lane = threadIdx.x & 63, wave = threadIdx.x >> 6;
  int base = 0;
  for (int i = 0; i < b; ++i) base += cnts[i];
  bool f = masks[gid] != 0;
  unsigned long long m = __ballot(f);
  __shared__ int wcnt[4];
  if (lane == 0) wcnt[wave] = __popcll(m);
  __syncthreads();
  int woff = 0;
  for (int i = 0; i < wave; ++i) woff += wcnt[i];
  if (f) list[base + woff + __popcll(m & ((1ull << lane) - 1ull))] = gid;
  if (b == 48 && threadIdx.x == 0)
    *total = base + wcnt[0] + wcnt[1] + wcnt[2] + wcnt[3];
}

// ---------------- stage 1: x -> masked bf16 NHWC4 padded ----------------
__global__ __launch_bounds__(256) void k_prep(const float* __restrict__ x, const int* __restrict__ masks,
                                              uint16_t* __restrict__ xp) {
  int gid = blockIdx.x * 256 + threadIdx.x;   // 64*232*232 = 3,444,736 exactly
  int b = gid / 53824;
  int rc = gid - b * 53824;
  int r2 = rc / 232;
  int c2 = rc - r2 * 232;
  int r = r2 - 3, c = c2 - 3;
  uint16_t o0 = 0, o1 = 0, o2 = 0;
  if ((unsigned)r < 224u && (unsigned)c < 224u) {
    if (masks[b * 196 + (r >> 4) * 14 + (c >> 4)]) {
      const float* px = x + (((size_t)b * 3) * 224 + r) * 224 + c;
      o0 = f2bf(px[0]);
      o1 = f2bf(px[50176]);
      o2 = f2bf(px[100352]);
    }
  }
  ushort4 o; o.x = o0; o.y = o1; o.z = o2; o.w = 0;
  *(ushort4*)(xp + (size_t)gid * 4) = o;
}

// ---------------- stage 2: weight transforms ----------------
__global__ __launch_bounds__(256) void k_wt(const float* __restrict__ w1, const float* __restrict__ w2,
                                            uint16_t* __restrict__ w1t, uint16_t* __restrict__ w2t) {
  int gid = blockIdx.x * 256 + threadIdx.x;   // 14336 + 2408448 = 2,422,784 exactly
  if (gid < 14336) {
    int kh = gid / 2048; int r = gid - kh * 2048;
    int oc = r >> 5, slot = r & 31;
    int kw = slot >> 2, ic = slot & 3;
    float v = 0.f;
    if (kw < 7 && ic < 3) v = w1[((oc * 3 + ic) * 7 + kh) * 7 + kw];
    w1t[gid] = f2bf(v);
  } else {
    int g2 = gid - 14336;
    int khw = g2 / 49152; int r = g2 - khw * 49152;
    int oc = r >> 6, ic = r & 63;
    int kh = khw / 7, kw = khw - kh * 7;
    w2t[g2] = f2bf(w2[((oc * 64 + ic) * 7 + kh) * 7 + kw]);
  }
}

// ---------------- stage 3: conv1 (7x7 s2) — barrier-free K-loop ----------------
__global__ __launch_bounds__(256, 3) void k_conv1(const uint16_t* __restrict__ xp, const uint16_t* __restrict__ w1t,
                                                  const int* __restrict__ list, const int* __restrict__ count,
                                                  uint16_t* __restrict__ y1) {
  __shared__ uint16_t sB[7 * 64 * 32];   // 28 KB: whole w1t resident
  __shared__ int sc[2];

  int cnt = *count;
  int blk = blockIdx.x;
  if (blk * 2 >= cnt) return;
  int tid = threadIdx.x, lane = tid & 63, wave = tid >> 6;
  int csw = (lane & 3) ^ ((lane >> 2) & 3);

  {
    const char* wg = (const char*)w1t;
    char* wl = (char*)sB;
#pragma unroll
    for (int t = 0; t < 7; ++t) {
      int ldsoff = t * 4096 + wave * 1024;
      int goff = t * 4096 + (wave * 16 + (lane >> 2)) * 64 + csw * 16;
      gl_lds16(wg + goff, wl + ldsoff);
    }
  }
  if (tid < 2) sc[tid] = list[imin(blk * 2 + tid, cnt - 1)];
  __syncthreads();

  int wm = wave * 32, mrow = lane & 15, kg = lane >> 4;

  const uint16_t* baseA[2];
#pragma unroll
  for (int i = 0; i < 2; ++i) {
    int row = wm + 16 * i + mrow;
    int cell = sc[row >> 6];
    int b = cell / 196, cc = cell - b * 196;
    int ci = cc / 14, cj = cc - ci * 14;
    int p = row & 63;
    int oh = ci * 8 + (p >> 3), ow = cj * 8 + (p & 7);
    baseA[i] = xp + (((size_t)(b * 232 + 2 * oh)) * 232 + 2 * ow) * 4 + kg * 8;
  }
  int ksw = (kg ^ (mrow & 3)) * 8;

  f32x4 acc[2][4];
#pragma unroll
  for (int i = 0; i < 2; ++i)
#pragma unroll
    for (int j = 0; j < 4; ++j) acc[i][j] = f32x4{0.f, 0.f, 0.f, 0.f};

#pragma unroll
  for (int kh = 0; kh < 7; ++kh) {
    short8 a0 = *(const short8*)(baseA[0] + kh * 928);
    short8 a1 = *(const short8*)(baseA[1] + kh * 928);
    const uint16_t* Bk = sB + kh * 2048;
#pragma unroll
    for (int j = 0; j < 4; ++j) {
      short8 bj = *(const short8*)(Bk + (16 * j + mrow) * 32 + ksw);
      acc[0][j] = mfma16(a0, bj, acc[0][j]);
      acc[1][j] = mfma16(a1, bj, acc[1][j]);
    }
  }

#pragma unroll
  for (int i = 0; i < 2; ++i) {
    int rbase = wm + 16 * i;
    int cellidx = blk * 2 + (rbase >> 6);
    if (cellidx >= cnt) continue;
    int cell = sc[rbase >> 6];
    int b = cell / 196, cc = cell - b * 196;
    int ci = cc / 14, cj = cc - ci * 14;
#pragma unroll
    for (int j = 0; j < 4; ++j) {
      int oc = 16 * j + mrow;
#pragma unroll
      for (int r = 0; r < 4; ++r) {
        int row = rbase + kg * 4 + r;
        int p = row & 63;
        int oh = ci * 8 + (p >> 3), ow = cj * 8 + (p & 7);
        float v = acc[i][j][r];
        v = v > 0.f ? v : 0.f;
        y1[(((size_t)(b * 112 + oh)) * 112 + ow) * 64 + oc] = f2bf(v);
      }
    }
  }
}

// ---------------- stage 4: MaxBlurPool1 (112 -> 56), mask-aware, writes padded p1 ----------------
__global__ __launch_bounds__(256) void k_pool1(const uint16_t* __restrict__ y1, const int* __restrict__ masks,
                                               uint16_t* __restrict__ p1) {
  __shared__ uint16_t sY[18 * 18 * 64];  // 41,472 B
  int b = blockIdx.y;
  int tile = blockIdx.x;
  int tr = tile >> 3, tc = tile & 7;
  int pr0 = tr * 8, pc0 = tc * 8;
  int R0 = 2 * pr0 - 7, C0 = 2 * pc0 - 7;
  int tid = threadIdx.x;
  const int* mb = masks + b * 196;

  for (int idx = tid; idx < 2592; idx += 256) {
    int pix = idx >> 3, ch = idx & 7;
    int pr = pix / 18, pc = pix - pr * 18;
    int r = R0 + pr, c = C0 + pc;
    short8 v = {0, 0, 0, 0, 0, 0, 0, 0};
    if ((unsigned)r < 112u && (unsigned)c < 112u && mb[(r >> 3) * 14 + (c >> 3)])
      v = *(const short8*)(y1 + (((size_t)(b * 112 + r)) * 112 + c) * 64 + ch * 8);
    *(short8*)(sY + ((size_t)(pr * 18 + pc)) * 64 + ch * 8) = v;
  }
  __syncthreads();

  for (int it = tid; it < 512; it += 256) {
    int opix = it >> 3, ch = it & 7;
    int lr = opix >> 3, lc = opix & 7;
    int pr = pr0 + lr, pc = pc0 + lc;
    if (pr >= 62 || pc >= 62) continue;
    int oh = pr - 3, ow = pc - 3;
    float acc[8] = {0.f, 0.f, 0.f, 0.f, 0.f, 0.f, 0.f, 0.f};
    if ((unsigned)oh < 56u && (unsigned)ow < 56u) {
      float hm_prev[3][8];
#pragma unroll
      for (int dd = 0; dd < 4; ++dd) {
        float yv[4][8];
        const uint16_t* src = sY + ((size_t)((2 * lr + dd) * 18 + 2 * lc)) * 64 + ch * 8;
#pragma unroll
        for (int e = 0; e < 4; ++e) {
          short8 t8 = *(const short8*)(src + e * 64);
#pragma unroll
          for (int k = 0; k < 8; ++k) yv[e][k] = bf2f((uint16_t)t8[k]);
        }
        float hm[3][8];
#pragma unroll
        for (int e = 0; e < 3; ++e) {
          int qc = 2 * ow - 1 + e;
          float cv = ((unsigned)qc <= 110u) ? 1.f : 0.f;
#pragma unroll
          for (int k = 0; k < 8; ++k) hm[e][k] = cv * fmaxf(yv[e][k], yv[e + 1][k]);
        }
        if (dd > 0) {
          int d = dd - 1;
          int qr = 2 * oh - 1 + d;
          if ((unsigned)qr <= 110u) {
            float wd = (d == 1) ? 2.f : 1.f;
#pragma unroll
            for (int e = 0; e < 3; ++e) {
              float w = wd * ((e == 1) ? 2.f : 1.f);
#pragma unroll
              for (int k = 0; k < 8; ++k) acc[k] += w * fmaxf(hm_prev[e][k], hm[e][k]);
            }
          }
        }
#pragma unroll
        for (int e = 0; e < 3; ++e)
#pragma unroll
          for (int k = 0; k < 8; ++k) hm_prev[e][k] = hm[e][k];
      }
#pragma unroll
      for (int k = 0; k < 8; ++k) acc[k] *= (1.f / 16.f);
    }
    short8 o;
#pragma unroll
    for (int k = 0; k < 8; ++k) o[k] = (short)f2bf(acc[k]);
    *(short8*)(p1 + (((size_t)(b * 62 + pr)) * 62 + pc) * 64 + ch * 8) = o;
  }
}

// ---------------- stage 5: conv2 (7x7 s2) — MFMA, M=256 x N=128 tile, XCD-grouped ----------------
// 512 threads = 8 waves, each a 64x64 quadrant (qm 0..3, qn 0..1). LDS-staged A (32 KB) +
// B^T (16 KB) per tap with XOR chunk swizzle (round-2 proven: 0 bank conflicts).
// Grid grouped so the 6 oc-slices of one mt land on one XCD consecutively -> A L2 reuse.
__global__ __launch_bounds__(512, 6) void k_conv2(const uint16_t* __restrict__ p1, const uint16_t* __restrict__ w2t,
                                                  const int* __restrict__ list, const int* __restrict__ count,
                                                  uint16_t* __restrict__ y2) {
  __shared__ uint16_t sA[256 * 64];   // 32 KB  A[row][ic]
  __shared__ uint16_t sBt[128 * 64];  // 16 KB  B^T[oc][ic]

  int cnt = *count;
  int gx = blockIdx.x;
  int xcd = gx & 7, s = gx >> 3;
  int y = s % 6, mtl = s / 6;
  int mt = xcd + 8 * mtl;            // 0..199
  if (mt * 64 >= cnt) return;
  int ocb = y * 128;
  int tid = threadIdx.x, lane = tid & 63, wave = tid >> 6;
  int csw = (lane & 7) ^ ((lane >> 3) & 7);

  // prologue: cells via sA scratch (sc would blow the 64 KB LDS budget)
  int* scs = (int*)sA;
  if (tid < 64) scs[tid] = list[imin(mt * 64 + tid, cnt - 1)];
  __syncthreads();
  int qm = wave & 3, qn = wave >> 2;
  int mrow = lane & 15, kg = lane >> 4;
  int cellA[4], cellE[4];
#pragma unroll
  for (int t = 0; t < 4; ++t) cellA[t] = scs[wave * 8 + t * 2 + (lane >> 5)];
#pragma unroll
  for (int i = 0; i < 4; ++i) cellE[i] = scs[qm * 16 + 4 * i + kg];
  __syncthreads();

  // staging base addresses (A: 4 insts/wave cover rows wave*32..+31; B: 2 insts cover oc rows wave*16..+15)
  const char* gA[4];
#pragma unroll
  for (int t = 0; t < 4; ++t) {
    int r = wave * 32 + t * 8 + (lane >> 3);
    int cell = cellA[t];
    int b = cell / 196, cc = cell - b * 196;
    int ci = cc / 14, cj = cc - ci * 14;
    int p = r & 3;
    int oh = 2 * ci + (p >> 1), ow = 2 * cj + (p & 1);
    gA[t] = (const char*)p1 + (((size_t)(b * 62 + 2 * oh)) * 62 + 2 * ow) * 128 + csw * 16;
  }
  const char* gB[2];
#pragma unroll
  for (int t = 0; t < 2; ++t) {
    int oc = ocb + wave * 16 + t * 8 + (lane >> 3);
    gB[t] = (const char*)w2t + (size_t)oc * 128 + csw * 16;
  }

  f32x4 acc[4][4];
#pragma unroll
  for (int i = 0; i < 4; ++i)
#pragma unroll
    for (int j = 0; j < 4; ++j) acc[i][j] = f32x4{0.f, 0.f, 0.f, 0.f};

  int sw = mrow & 7;
  int kh = 0, kw = 0;

#pragma unroll 1
  for (int it = 0; it < 49; ++it) {
    size_t offA = (size_t)(kh * 62 + kw) * 128;
    size_t offB = (size_t)it * 98304;   // 768*64 elems * 2 B per tap
    char* la = (char*)sA + (wave * 32) * 128;
    char* lb = (char*)sBt + (wave * 16) * 128;
#pragma unroll
    for (int t = 0; t < 4; ++t) gl_lds16(gA[t] + offA, la + t * 1024);
#pragma unroll
    for (int t = 0; t < 2; ++t) gl_lds16(gB[t] + offB, lb + t * 1024);
    __syncthreads();
#pragma unroll
    for (int ks = 0; ks < 2; ++ks) {
      int koff = ((ks * 4 + kg) ^ sw) * 8;
      short8 a[4], bb[4];
#pragma unroll
      for (int i = 0; i < 4; ++i)
        a[i] = *(const short8*)(sA + (qm * 64 + 16 * i + mrow) * 64 + koff);
#pragma unroll
      for (int j = 0; j < 4; ++j)
        bb[j] = *(const short8*)(sBt + (qn * 64 + 16 * j + mrow) * 64 + koff);
#pragma unroll
      for (int i = 0; i < 4; ++i)
#pragma unroll
        for (int j = 0; j < 4; ++j)
          acc[i][j] = mfma16(a[i], bb[j], acc[i][j]);
    }
    __syncthreads();
    if (++kw == 7) { kw = 0; ++kh; }
  }

  // epilogue: relu, write y2 NHWC bf16 (active rows only)
#pragma unroll
  for (int i = 0; i < 4; ++i) {
    int cellslot = qm * 16 + 4 * i + kg;
    int cellidx = mt * 64 + cellslot;
    if (cellidx >= cnt) continue;
    int cell = cellE[i];
    int b = cell / 196, cc = cell - b * 196;
    int ci = cc / 14, cj = cc - ci * 14;
#pragma unroll
    for (int j = 0; j < 4; ++j) {
      int oc = ocb + qn * 64 + 16 * j + mrow;
#pragma unroll
      for (int r = 0; r < 4; ++r) {
        int oh = 2 * ci + (r >> 1), ow = 2 * cj + (r & 1);
        float v = acc[i][j][r];
        v = v > 0.f ? v : 0.f;
        y2[(((size_t)(b * 784)) + oh * 28 + ow) * 768 + oc] = f2bf(v);
      }
    }
  }
}

// ---------------- stage 6: MaxBlurPool2 (28 -> 14) + transpose to [B,196,768] fp32 ----------------
__global__ __launch_bounds__(256) void k_pool2(const uint16_t* __restrict__ y2, const int* __restrict__ masks,
                                               float* __restrict__ out) {
  __shared__ uint16_t sY[4 * 28 * 128];   // 28,672 B
  int chunk = blockIdx.x, pi = blockIdx.y, b = blockIdx.z;
  int ch0 = chunk * 128;
  int tid = threadIdx.x;
  const int* mb = masks + b * 196;

  for (int idx = tid; idx < 1792; idx += 256) {
    int rc = idx >> 4;
    int sub = idx & 15;
    int k = rc / 28, c = rc - k * 28;
    int r = 2 * pi - 1 + k;
    short8 v = {0, 0, 0, 0, 0, 0, 0, 0};
    if ((unsigned)r < 28u && mb[(r >> 1) * 14 + (c >> 1)])
      v = *(const short8*)(y2 + (((size_t)(b * 784)) + r * 28 + c) * 768 + ch0 + sub * 8);
    *(short8*)(sY + ((size_t)(k * 28 + c)) * 128 + sub * 8) = v;
  }
  __syncthreads();

  for (int idx = tid; idx < 1792; idx += 256) {
    int pj = idx >> 7, ch = idx & 127;
    float v[4][4];
#pragma unroll
    for (int e = 0; e < 4; ++e) {
      int col = 2 * pj - 1 + e;
      bool cv = (unsigned)col < 28u;
#pragma unroll
      for (int k = 0; k < 4; ++k)
        v[k][e] = cv ? bf2f(sY[((size_t)(k * 28 + col)) * 128 + ch]) : 0.f;
    }
    float acc = 0.f;
#pragma unroll
    for (int d = 0; d < 3; ++d) {
      int q = 2 * pi - 1 + d;
      float gd = ((unsigned)q <= 26u) ? ((d == 1) ? 2.f : 1.f) : 0.f;
      float s = 0.f;
#pragma unroll
      for (int e = 0; e < 3; ++e) {
        int q2 = 2 * pj - 1 + e;
        float ge = ((unsigned)q2 <= 26u) ? ((e == 1) ? 2.f : 1.f) : 0.f;
        float m = fmaxf(fmaxf(v[d][e], v[d + 1][e]), fmaxf(v[d][e + 1], v[d + 1][e + 1]));
        s += ge * m;
      }
      acc += gd * s;
    }
    out[(((size_t)(b * 196)) + pi * 14 + pj) * 768 + ch0 + ch] = acc * (1.f / 16.f);
  }
}

// ---------------- launcher ----------------
extern "C" void kernel_launch(void* const* d_in, const int* in_sizes, int n_in,
                              void* d_out, int out_size, void* d_ws, size_t ws_size,
                              hipStream_t stream) {
  const float* x     = (const float*)d_in[0];
  const int*   masks = (const int*)d_in[1];
  const float* w1    = (const float*)d_in[2];
  const float* w2    = (const float*)d_in[3];

  char* ws = (char*)d_ws;
  if (ws_size < WS_NEED) return;

  uint16_t* xp  = (uint16_t*)(ws + OFF_XP);
  uint16_t* w1t = (uint16_t*)(ws + OFF_W1T);
  uint16_t* w2t = (uint16_t*)(ws + OFF_W2T);
  uint16_t* y1  = (uint16_t*)(ws + OFF_Y1);
  uint16_t* p1  = (uint16_t*)(ws + OFF_P1);
  uint16_t* y2  = (uint16_t*)(ws + OFF_Y2);
  int* list     = (int*)(ws + OFF_LIST);
  int* cnts     = (int*)(ws + OFF_CNT);
  int* total    = cnts + 49;

  k_count<<<49, 256, 0, stream>>>(masks, cnts);
  k_emit<<<49, 256, 0, stream>>>(masks, cnts, list, total);
  k_prep<<<13456, 256, 0, stream>>>(x, masks, xp);
  k_wt<<<9464, 256, 0, stream>>>(w1, w2, w1t, w2t);
  k_conv1<<<6272, 256, 0, stream>>>(xp, w1t, list, total, y1);
  k_pool1<<<dim3(64, 64), 256, 0, stream>>>(y1, masks, p1);
  // 8 XCD groups x 25 mt-slots x 6 oc-slices = 1200 blocks; 6 slices of an mt are
  // consecutive same-XCD ids (gx = xcd + 8*(mtl*6 + y)) for A-tile L2 reuse.
  k_conv2<<<1200, 512, 0, stream>>>(p1, w2t, list, total, y2);
  k_pool2<<<dim3(6, 14, 64), 256, 0, stream>>>(y2, masks, (float*)d_out);
}

// Round 5
// 395.335 us; speedup vs baseline: 2.5789x; 2.5789x over previous
//
#include <hip/hip_runtime.h>
#include <stdint.h>

typedef __attribute__((ext_vector_type(8))) short short8;
typedef __attribute__((ext_vector_type(4))) float f32x4;

#define DEVFN static __device__ __forceinline__

// ---------------- helpers ----------------
DEVFN float bf2f(uint16_t u) { union { uint32_t i; float f; } v; v.i = ((uint32_t)u) << 16; return v.f; }
DEVFN uint16_t f2bf(float f) {
  union { float f; uint32_t i; } v; v.f = f;
  uint32_t u = v.i;
  u += 0x7fffu + ((u >> 16) & 1u);   // RNE
  return (uint16_t)(u >> 16);
}
DEVFN int imin(int a, int b) { return a < b ? a : b; }

DEVFN void gl_lds16(const void* g, void* l) {
  __builtin_amdgcn_global_load_lds(
      (__attribute__((address_space(1))) void*)(void*)g,
      (__attribute__((address_space(3))) void*)l, 16, 0, 0);
}

DEVFN f32x4 mfma16(short8 a, short8 b, f32x4 c) {
  return __builtin_amdgcn_mfma_f32_16x16x32_bf16(a, b, c, 0, 0, 0);
}

// ---------------- workspace layout (bytes) ----------------
static constexpr size_t OFF_XP   = 0;          // bf16 [64][232][232][4]  x: masked, padded(+3), NHWC4
static constexpr size_t OFF_W1T  = 27557888;   // bf16 [7][64][32]        w1t[kh][oc][kw*4+ic]
static constexpr size_t OFF_W2T  = 27586560;   // bf16 [49][768][64]      w2t[kh*7+kw][oc][ic]
static constexpr size_t OFF_Y1   = 32403456;   // bf16 [64][112][112][64] conv1 out (active cells only)
static constexpr size_t OFF_P1   = 135163904;  // bf16 [64][62][62][64]   pool1 out, padded(+3), NHWC
static constexpr size_t OFF_Y2   = 166653952;  // bf16 [64][28][28][768]  conv2 out (active cells only)
static constexpr size_t OFF_LIST = 243724288;  // int [12544] active cell list, SORTED
static constexpr size_t OFF_CNT  = 243774464;  // int cnts[49] + int total
static constexpr size_t WS_NEED  = 243774664;

// ---------------- stage 0a: per-block mask counts ----------------
__global__ __launch_bounds__(256) void k_count(const int* __restrict__ masks, int* __restrict__ cnts) {
  int b = blockIdx.x;
  int gid = b * 256 + threadIdx.x;   // 49*256 = 12544 exactly
  unsigned long long m = __ballot(masks[gid] != 0);
  __shared__ int wsum[4];
  if ((threadIdx.x & 63) == 0) wsum[threadIdx.x >> 6] = __popcll(m);
  __syncthreads();
  if (threadIdx.x == 0) cnts[b] = wsum[0] + wsum[1] + wsum[2] + wsum[3];
}

// ---------------- stage 0b: deterministic sorted compaction ----------------
__global__ __launch_bounds__(256) void k_emit(const int* __restrict__ masks, const int* __restrict__ cnts,
                                              int* __restrict__ list, int* __restrict__ total) {
  int b = blockIdx.x;
  int gid = b * 256 + threadIdx.x;
  int lane = threadIdx.x & 63, wave = threadIdx.x >> 6;
  int base = 0;
  for (int i = 0; i < b; ++i) base += cnts[i];
  bool f = masks[gid] != 0;
  unsigned long long m = __ballot(f);
  __shared__ int wcnt[4];
  if (lane == 0) wcnt[wave] = __popcll(m);
  __syncthreads();
  int woff = 0;
  for (int i = 0; i < wave; ++i) woff += wcnt[i];
  if (f) list[base + woff + __popcll(m & ((1ull << lane) - 1ull))] = gid;
  if (b == 48 && threadIdx.x == 0)
    *total = base + wcnt[0] + wcnt[1] + wcnt[2] + wcnt[3];
}

// ---------------- stage 1: x -> masked bf16 NHWC4 padded ----------------
__global__ __launch_bounds__(256) void k_prep(const float* __restrict__ x, const int* __restrict__ masks,
                                              uint16_t* __restrict__ xp) {
  int gid = blockIdx.x * 256 + threadIdx.x;   // 64*232*232 = 3,444,736 exactly
  int b = gid / 53824;
  int rc = gid - b * 53824;
  int r2 = rc / 232;
  int c2 = rc - r2 * 232;
  int r = r2 - 3, c = c2 - 3;
  uint16_t o0 = 0, o1 = 0, o2 = 0;
  if ((unsigned)r < 224u && (unsigned)c < 224u) {
    if (masks[b * 196 + (r >> 4) * 14 + (c >> 4)]) {
      const float* px = x + (((size_t)b * 3) * 224 + r) * 224 + c;
      o0 = f2bf(px[0]);
      o1 = f2bf(px[50176]);
      o2 = f2bf(px[100352]);
    }
  }
  ushort4 o; o.x = o0; o.y = o1; o.z = o2; o.w = 0;
  *(ushort4*)(xp + (size_t)gid * 4) = o;
}

// ---------------- stage 2: weight transforms ----------------
__global__ __launch_bounds__(256) void k_wt(const float* __restrict__ w1, const float* __restrict__ w2,
                                            uint16_t* __restrict__ w1t, uint16_t* __restrict__ w2t) {
  int gid = blockIdx.x * 256 + threadIdx.x;   // 14336 + 2408448 = 2,422,784 exactly
  if (gid < 14336) {
    int kh = gid / 2048; int r = gid - kh * 2048;
    int oc = r >> 5, slot = r & 31;
    int kw = slot >> 2, ic = slot & 3;
    float v = 0.f;
    if (kw < 7 && ic < 3) v = w1[((oc * 3 + ic) * 7 + kh) * 7 + kw];
    w1t[gid] = f2bf(v);
  } else {
    int g2 = gid - 14336;
    int khw = g2 / 49152; int r = g2 - khw * 49152;
    int oc = r >> 6, ic = r & 63;
    int kh = khw / 7, kw = khw - kh * 7;
    w2t[g2] = f2bf(w2[((oc * 64 + ic) * 7 + kh) * 7 + kw]);
  }
}

// ---------------- stage 3: conv1 (7x7 s2) — barrier-free K-loop ----------------
__global__ __launch_bounds__(256, 3) void k_conv1(const uint16_t* __restrict__ xp, const uint16_t* __restrict__ w1t,
                                                  const int* __restrict__ list, const int* __restrict__ count,
                                                  uint16_t* __restrict__ y1) {
  __shared__ uint16_t sB[7 * 64 * 32];   // 28 KB: whole w1t resident
  __shared__ int sc[2];

  int cnt = *count;
  int blk = blockIdx.x;
  if (blk * 2 >= cnt) return;
  int tid = threadIdx.x, lane = tid & 63, wave = tid >> 6;
  int csw = (lane & 3) ^ ((lane >> 2) & 3);

  {
    const char* wg = (const char*)w1t;
    char* wl = (char*)sB;
#pragma unroll
    for (int t = 0; t < 7; ++t) {
      int ldsoff = t * 4096 + wave * 1024;
      int goff = t * 4096 + (wave * 16 + (lane >> 2)) * 64 + csw * 16;
      gl_lds16(wg + goff, wl + ldsoff);
    }
  }
  if (tid < 2) sc[tid] = list[imin(blk * 2 + tid, cnt - 1)];
  __syncthreads();

  int wm = wave * 32, mrow = lane & 15, kg = lane >> 4;

  const uint16_t* baseA[2];
#pragma unroll
  for (int i = 0; i < 2; ++i) {
    int row = wm + 16 * i + mrow;
    int cell = sc[row >> 6];
    int b = cell / 196, cc = cell - b * 196;
    int ci = cc / 14, cj = cc - ci * 14;
    int p = row & 63;
    int oh = ci * 8 + (p >> 3), ow = cj * 8 + (p & 7);
    baseA[i] = xp + (((size_t)(b * 232 + 2 * oh)) * 232 + 2 * ow) * 4 + kg * 8;
  }
  int ksw = (kg ^ (mrow & 3)) * 8;

  f32x4 acc[2][4];
#pragma unroll
  for (int i = 0; i < 2; ++i)
#pragma unroll
    for (int j = 0; j < 4; ++j) acc[i][j] = f32x4{0.f, 0.f, 0.f, 0.f};

#pragma unroll
  for (int kh = 0; kh < 7; ++kh) {
    short8 a0 = *(const short8*)(baseA[0] + kh * 928);
    short8 a1 = *(const short8*)(baseA[1] + kh * 928);
    const uint16_t* Bk = sB + kh * 2048;
#pragma unroll
    for (int j = 0; j < 4; ++j) {
      short8 bj = *(const short8*)(Bk + (16 * j + mrow) * 32 + ksw);
      acc[0][j] = mfma16(a0, bj, acc[0][j]);
      acc[1][j] = mfma16(a1, bj, acc[1][j]);
    }
  }

#pragma unroll
  for (int i = 0; i < 2; ++i) {
    int rbase = wm + 16 * i;
    int cellidx = blk * 2 + (rbase >> 6);
    if (cellidx >= cnt) continue;
    int cell = sc[rbase >> 6];
    int b = cell / 196, cc = cell - b * 196;
    int ci = cc / 14, cj = cc - ci * 14;
#pragma unroll
    for (int j = 0; j < 4; ++j) {
      int oc = 16 * j + mrow;
#pragma unroll
      for (int r = 0; r < 4; ++r) {
        int row = rbase + kg * 4 + r;
        int p = row & 63;
        int oh = ci * 8 + (p >> 3), ow = cj * 8 + (p & 7);
        float v = acc[i][j][r];
        v = v > 0.f ? v : 0.f;
        y1[(((size_t)(b * 112 + oh)) * 112 + ow) * 64 + oc] = f2bf(v);
      }
    }
  }
}

// ---------------- stage 4: MaxBlurPool1 (112 -> 56), mask-aware, writes padded p1 ----------------
__global__ __launch_bounds__(256) void k_pool1(const uint16_t* __restrict__ y1, const int* __restrict__ masks,
                                               uint16_t* __restrict__ p1) {
  __shared__ uint16_t sY[18 * 18 * 64];  // 41,472 B
  int b = blockIdx.y;
  int tile = blockIdx.x;
  int tr = tile >> 3, tc = tile & 7;
  int pr0 = tr * 8, pc0 = tc * 8;
  int R0 = 2 * pr0 - 7, C0 = 2 * pc0 - 7;
  int tid = threadIdx.x;
  const int* mb = masks + b * 196;

  for (int idx = tid; idx < 2592; idx += 256) {
    int pix = idx >> 3, ch = idx & 7;
    int pr = pix / 18, pc = pix - pr * 18;
    int r = R0 + pr, c = C0 + pc;
    short8 v = {0, 0, 0, 0, 0, 0, 0, 0};
    if ((unsigned)r < 112u && (unsigned)c < 112u && mb[(r >> 3) * 14 + (c >> 3)])
      v = *(const short8*)(y1 + (((size_t)(b * 112 + r)) * 112 + c) * 64 + ch * 8);
    *(short8*)(sY + ((size_t)(pr * 18 + pc)) * 64 + ch * 8) = v;
  }
  __syncthreads();

  for (int it = tid; it < 512; it += 256) {
    int opix = it >> 3, ch = it & 7;
    int lr = opix >> 3, lc = opix & 7;
    int pr = pr0 + lr, pc = pc0 + lc;
    if (pr >= 62 || pc >= 62) continue;
    int oh = pr - 3, ow = pc - 3;
    float acc[8] = {0.f, 0.f, 0.f, 0.f, 0.f, 0.f, 0.f, 0.f};
    if ((unsigned)oh < 56u && (unsigned)ow < 56u) {
      float hm_prev[3][8];
#pragma unroll
      for (int dd = 0; dd < 4; ++dd) {
        float yv[4][8];
        const uint16_t* src = sY + ((size_t)((2 * lr + dd) * 18 + 2 * lc)) * 64 + ch * 8;
#pragma unroll
        for (int e = 0; e < 4; ++e) {
          short8 t8 = *(const short8*)(src + e * 64);
#pragma unroll
          for (int k = 0; k < 8; ++k) yv[e][k] = bf2f((uint16_t)t8[k]);
        }
        float hm[3][8];
#pragma unroll
        for (int e = 0; e < 3; ++e) {
          int qc = 2 * ow - 1 + e;
          float cv = ((unsigned)qc <= 110u) ? 1.f : 0.f;
#pragma unroll
          for (int k = 0; k < 8; ++k) hm[e][k] = cv * fmaxf(yv[e][k], yv[e + 1][k]);
        }
        if (dd > 0) {
          int d = dd - 1;
          int qr = 2 * oh - 1 + d;
          if ((unsigned)qr <= 110u) {
            float wd = (d == 1) ? 2.f : 1.f;
#pragma unroll
            for (int e = 0; e < 3; ++e) {
              float w = wd * ((e == 1) ? 2.f : 1.f);
#pragma unroll
              for (int k = 0; k < 8; ++k) acc[k] += w * fmaxf(hm_prev[e][k], hm[e][k]);
            }
          }
        }
#pragma unroll
        for (int e = 0; e < 3; ++e)
#pragma unroll
          for (int k = 0; k < 8; ++k) hm_prev[e][k] = hm[e][k];
      }
#pragma unroll
      for (int k = 0; k < 8; ++k) acc[k] *= (1.f / 16.f);
    }
    short8 o;
#pragma unroll
    for (int k = 0; k < 8; ++k) o[k] = (short)f2bf(acc[k]);
    *(short8*)(p1 + (((size_t)(b * 62 + pr)) * 62 + pc) * 64 + ch * 8) = o;
  }
}

// ---------------- stage 5: conv2 (7x7 s2) — MFMA, M=256 x N=128 tile, XCD-grouped ----------------
// 512 threads = 8 waves, each a 64x64 quadrant (qm 0..3, qn 0..1). LDS-staged A (32 KB) +
// B^T (16 KB) per tap with XOR chunk swizzle (round-2 proven: 0 bank conflicts).
// __launch_bounds__(512, 4): 128-VGPR cap — acc[4][4] needs 64 VGPRs; R4's (512,6)
// clamped to ~85 and SPILLED (WRITE_SIZE 1.6 GB, MfmaUtil 6%). Never bound below 128 here.
__global__ __launch_bounds__(512, 4) void k_conv2(const uint16_t* __restrict__ p1, const uint16_t* __restrict__ w2t,
                                                  const int* __restrict__ list, const int* __restrict__ count,
                                                  uint16_t* __restrict__ y2) {
  __shared__ uint16_t sA[256 * 64];   // 32 KB  A[row][ic]
  __shared__ uint16_t sBt[128 * 64];  // 16 KB  B^T[oc][ic]

  int cnt = *count;
  int gx = blockIdx.x;
  int xcd = gx & 7, s = gx >> 3;
  int y = s % 6, mtl = s / 6;
  int mt = xcd + 8 * mtl;            // 0..199
  if (mt * 64 >= cnt) return;
  int ocb = y * 128;
  int tid = threadIdx.x, lane = tid & 63, wave = tid >> 6;
  int csw = (lane & 7) ^ ((lane >> 3) & 7);

  // prologue: cells via sA scratch
  int* scs = (int*)sA;
  if (tid < 64) scs[tid] = list[imin(mt * 64 + tid, cnt - 1)];
  __syncthreads();
  int qm = wave & 3, qn = wave >> 2;
  int mrow = lane & 15, kg = lane >> 4;
  int cellA[4], cellE[4];
#pragma unroll
  for (int t = 0; t < 4; ++t) cellA[t] = scs[wave * 8 + t * 2 + (lane >> 5)];
#pragma unroll
  for (int i = 0; i < 4; ++i) cellE[i] = scs[qm * 16 + 4 * i + kg];
  __syncthreads();

  const char* gA[4];
#pragma unroll
  for (int t = 0; t < 4; ++t) {
    int r = wave * 32 + t * 8 + (lane >> 3);
    int cell = cellA[t];
    int b = cell / 196, cc = cell - b * 196;
    int ci = cc / 14, cj = cc - ci * 14;
    int p = r & 3;
    int oh = 2 * ci + (p >> 1), ow = 2 * cj + (p & 1);
    gA[t] = (const char*)p1 + (((size_t)(b * 62 + 2 * oh)) * 62 + 2 * ow) * 128 + csw * 16;
  }
  const char* gB[2];
#pragma unroll
  for (int t = 0; t < 2; ++t) {
    int oc = ocb + wave * 16 + t * 8 + (lane >> 3);
    gB[t] = (const char*)w2t + (size_t)oc * 128 + csw * 16;
  }

  f32x4 acc[4][4];
#pragma unroll
  for (int i = 0; i < 4; ++i)
#pragma unroll
    for (int j = 0; j < 4; ++j) acc[i][j] = f32x4{0.f, 0.f, 0.f, 0.f};

  int sw = mrow & 7;
  int kh = 0, kw = 0;

#pragma unroll 1
  for (int it = 0; it < 49; ++it) {
    size_t offA = (size_t)(kh * 62 + kw) * 128;
    size_t offB = (size_t)it * 98304;   // 768*64 elems * 2 B per tap
    char* la = (char*)sA + (wave * 32) * 128;
    char* lb = (char*)sBt + (wave * 16) * 128;
#pragma unroll
    for (int t = 0; t < 4; ++t) gl_lds16(gA[t] + offA, la + t * 1024);
#pragma unroll
    for (int t = 0; t < 2; ++t) gl_lds16(gB[t] + offB, lb + t * 1024);
    __syncthreads();
#pragma unroll
    for (int ks = 0; ks < 2; ++ks) {
      int koff = ((ks * 4 + kg) ^ sw) * 8;
      short8 a[4], bb[4];
#pragma unroll
      for (int i = 0; i < 4; ++i)
        a[i] = *(const short8*)(sA + (qm * 64 + 16 * i + mrow) * 64 + koff);
#pragma unroll
      for (int j = 0; j < 4; ++j)
        bb[j] = *(const short8*)(sBt + (qn * 64 + 16 * j + mrow) * 64 + koff);
#pragma unroll
      for (int i = 0; i < 4; ++i)
#pragma unroll
        for (int j = 0; j < 4; ++j)
          acc[i][j] = mfma16(a[i], bb[j], acc[i][j]);
    }
    __syncthreads();
    if (++kw == 7) { kw = 0; ++kh; }
  }

  // epilogue: relu, write y2 NHWC bf16 (active rows only)
#pragma unroll
  for (int i = 0; i < 4; ++i) {
    int cellslot = qm * 16 + 4 * i + kg;
    int cellidx = mt * 64 + cellslot;
    if (cellidx >= cnt) continue;
    int cell = cellE[i];
    int b = cell / 196, cc = cell - b * 196;
    int ci = cc / 14, cj = cc - ci * 14;
#pragma unroll
    for (int j = 0; j < 4; ++j) {
      int oc = ocb + qn * 64 + 16 * j + mrow;
#pragma unroll
      for (int r = 0; r < 4; ++r) {
        int oh = 2 * ci + (r >> 1), ow = 2 * cj + (r & 1);
        float v = acc[i][j][r];
        v = v > 0.f ? v : 0.f;
        y2[(((size_t)(b * 784)) + oh * 28 + ow) * 768 + oc] = f2bf(v);
      }
    }
  }
}

// ---------------- stage 6: MaxBlurPool2 (28 -> 14) + transpose to [B,196,768] fp32 ----------------
__global__ __launch_bounds__(256) void k_pool2(const uint16_t* __restrict__ y2, const int* __restrict__ masks,
                                               float* __restrict__ out) {
  __shared__ uint16_t sY[4 * 28 * 128];   // 28,672 B
  int chunk = blockIdx.x, pi = blockIdx.y, b = blockIdx.z;
  int ch0 = chunk * 128;
  int tid = threadIdx.x;
  const int* mb = masks + b * 196;

  for (int idx = tid; idx < 1792; idx += 256) {
    int rc = idx >> 4;
    int sub = idx & 15;
    int k = rc / 28, c = rc - k * 28;
    int r = 2 * pi - 1 + k;
    short8 v = {0, 0, 0, 0, 0, 0, 0, 0};
    if ((unsigned)r < 28u && mb[(r >> 1) * 14 + (c >> 1)])
      v = *(const short8*)(y2 + (((size_t)(b * 784)) + r * 28 + c) * 768 + ch0 + sub * 8);
    *(short8*)(sY + ((size_t)(k * 28 + c)) * 128 + sub * 8) = v;
  }
  __syncthreads();

  for (int idx = tid; idx < 1792; idx += 256) {
    int pj = idx >> 7, ch = idx & 127;
    float v[4][4];
#pragma unroll
    for (int e = 0; e < 4; ++e) {
      int col = 2 * pj - 1 + e;
      bool cv = (unsigned)col < 28u;
#pragma unroll
      for (int k = 0; k < 4; ++k)
        v[k][e] = cv ? bf2f(sY[((size_t)(k * 28 + col)) * 128 + ch]) : 0.f;
    }
    float acc = 0.f;
#pragma unroll
    for (int d = 0; d < 3; ++d) {
      int q = 2 * pi - 1 + d;
      float gd = ((unsigned)q <= 26u) ? ((d == 1) ? 2.f : 1.f) : 0.f;
      float s = 0.f;
#pragma unroll
      for (int e = 0; e < 3; ++e) {
        int q2 = 2 * pj - 1 + e;
        float ge = ((unsigned)q2 <= 26u) ? ((e == 1) ? 2.f : 1.f) : 0.f;
        float m = fmaxf(fmaxf(v[d][e], v[d + 1][e]), fmaxf(v[d][e + 1], v[d + 1][e + 1]));
        s += ge * m;
      }
      acc += gd * s;
    }
    out[(((size_t)(b * 196)) + pi * 14 + pj) * 768 + ch0 + ch] = acc * (1.f / 16.f);
  }
}

// ---------------- launcher ----------------
extern "C" void kernel_launch(void* const* d_in, const int* in_sizes, int n_in,
                              void* d_out, int out_size, void* d_ws, size_t ws_size,
                              hipStream_t stream) {
  const float* x     = (const float*)d_in[0];
  const int*   masks = (const int*)d_in[1];
  const float* w1    = (const float*)d_in[2];
  const float* w2    = (const float*)d_in[3];

  char* ws = (char*)d_ws;
  if (ws_size < WS_NEED) return;

  uint16_t* xp  = (uint16_t*)(ws + OFF_XP);
  uint16_t* w1t = (uint16_t*)(ws + OFF_W1T);
  uint16_t* w2t = (uint16_t*)(ws + OFF_W2T);
  uint16_t* y1  = (uint16_t*)(ws + OFF_Y1);
  uint16_t* p1  = (uint16_t*)(ws + OFF_P1);
  uint16_t* y2  = (uint16_t*)(ws + OFF_Y2);
  int* list     = (int*)(ws + OFF_LIST);
  int* cnts     = (int*)(ws + OFF_CNT);
  int* total    = cnts + 49;

  k_count<<<49, 256, 0, stream>>>(masks, cnts);
  k_emit<<<49, 256, 0, stream>>>(masks, cnts, list, total);
  k_prep<<<13456, 256, 0, stream>>>(x, masks, xp);
  k_wt<<<9464, 256, 0, stream>>>(w1, w2, w1t, w2t);
  k_conv1<<<6272, 256, 0, stream>>>(xp, w1t, list, total, y1);
  k_pool1<<<dim3(64, 64), 256, 0, stream>>>(y1, masks, p1);
  // 8 XCD groups x 25 mt-slots x 6 oc-slices = 1200 blocks; 6 slices of an mt are
  // consecutive same-XCD ids (gx = xcd + 8*(mtl*6 + y)) for A-tile L2 reuse.
  k_conv2<<<1200, 512, 0, stream>>>(p1, w2t, list, total, y2);
  k_pool2<<<dim3(6, 14, 64), 256, 0, stream>>>(y2, masks, (float*)d_out);
}